// Round 1
// 432.595 us; speedup vs baseline: 1.1564x; 1.1564x over previous
//
#include <hip/hip_runtime.h>

// TranslateCube: out[n, y, x] = bilinear sample of img[n] at (y - dy[n], x - dx[n]),
// zero fill outside. B*T = 1024 images, H = W = 256, fp32.
//
// v2: LDS row-band staging.
//   - tx/ty are uniform per image, so a 16-row output band needs only a
//     contiguous window of <=18 source rows (fp32 floor wobble gives RB+2 max).
//   - Stage that window into LDS with coalesced float4 loads (zero-filled for
//     out-of-image rows -> y-validity checks disappear).
//   - Each pixel then does 4 stride-1 LDS reads (conflict-free) instead of
//     4 narrow global gathers.  Per-pixel fp32 arithmetic is IDENTICAL to the
//     reference / previous kernel (same expression tree), so results are
//     bit-identical; only the load path changed.
//
// Mapping: grid = (B*T) * (H/RB) blocks, 256 threads.
//   blockIdx.x >> 4  -> image index n
//   blockIdx.x & 15  -> row-band index (16 bands of 16 rows)
//   wave wv (tid>>6) handles rows wv*4..wv*4+3; lanes sweep 4x64 columns.

constexpr int HH = 256;
constexpr int WW = 256;
constexpr int RB = 16;          // output rows per block
constexpr int SROWS = RB + 2;   // staged source rows (floor() wobble bound)

__global__ __launch_bounds__(256) void translate_kernel(
    const float* __restrict__ img,
    const float* __restrict__ dx,
    const float* __restrict__ dy,
    float* __restrict__ out)
{
    __shared__ float lds[SROWS][WW];   // 18 KB -> 8 blocks/CU, full occupancy

    const int n  = blockIdx.x >> 4;          // image index
    const int yb = (blockIdx.x & 15) * RB;   // first output row of this band

    const float tx = dx[n];   // wave-uniform -> scalar loads
    const float ty = dy[n];

    // Source-row window. Computed with the SAME fp32 ops as the per-row floor
    // below; fp rounding is monotone, so every row's y0 lands in [rmin, rmax-1]
    // and y0+1 <= rmax.  rmax - rmin <= 17 (RB-1 real span + 1 + rounding).
    const int rmin = (int)floorf((float)yb - ty);
    const int rmax = (int)floorf((float)(yb + RB - 1) - ty) + 1;
    const int nrows = rmax - rmin + 1;       // <= SROWS

    // ---- Stage source rows [rmin, rmax] into LDS (zero-fill outside image) ----
    const int tid = threadIdx.x;
    {
        const float4* __restrict__ img4 =
            (const float4*)(img + (size_t)n * (HH * WW));
        float4* lds4 = (float4*)&lds[0][0];
        const int total = nrows * (WW / 4);          // float4s to stage
        for (int idx = tid; idx < total; idx += 256) {
            const int rr   = idx >> 6;               // staged row
            const int cc   = idx & 63;               // float4 within row
            const int srow = rmin + rr;              // source image row
            float4 v = make_float4(0.f, 0.f, 0.f, 0.f);
            if ((unsigned)srow < (unsigned)HH)
                v = img4[srow * (WW / 4) + cc];
            lds4[idx] = v;
        }
    }
    __syncthreads();

    // ---- Compute 16 rows x 256 cols from LDS ----
    const int lane = tid & 63;
    const int wv   = tid >> 6;

    #pragma unroll
    for (int jr = 0; jr < 4; ++jr) {
        const int r = (wv << 2) | jr;                // row within band
        const int y = yb + r;

        const float ysf = (float)y - ty;             // same fp32 ops as reference
        const float y0f = floorf(ysf);
        const float wy  = ysf - y0f;
        const int   ly0 = (int)y0f - rmin;           // in [0, nrows-2]
        const float* __restrict__ L0 = &lds[ly0][0];
        const float* __restrict__ L1 = &lds[ly0 + 1][0];
        float* __restrict__ orow = out + ((size_t)n * HH + y) * WW;

        #pragma unroll
        for (int k = 0; k < 4; ++k) {
            const int x = (k << 6) | lane;           // stride-1 across lanes
            const float xsf = (float)x - tx;
            const float x0f = floorf(xsf);
            const float wx  = xsf - x0f;
            const int x0 = (int)x0f;
            const int x1 = x0 + 1;
            const bool vx0 = ((unsigned)x0 < (unsigned)WW);
            const bool vx1 = ((unsigned)x1 < (unsigned)WW);
            const int xc0 = min(max(x0, 0), WW - 1);
            const int xc1 = min(max(x1, 0), WW - 1);

            // Stride-1 LDS reads: 2 lanes/bank -> conflict-free.
            const float c00 = vx0 ? L0[xc0] : 0.0f;
            const float c01 = vx1 ? L0[xc1] : 0.0f;
            const float c10 = vx0 ? L1[xc0] : 0.0f;
            const float c11 = vx1 ? L1[xc1] : 0.0f;

            const float top = (1.0f - wx) * c00 + wx * c01;
            const float bot = (1.0f - wx) * c10 + wx * c11;
            orow[x] = (1.0f - wy) * top + wy * bot;  // coalesced 4B store
        }
    }
}

extern "C" void kernel_launch(void* const* d_in, const int* in_sizes, int n_in,
                              void* d_out, int out_size, void* d_ws, size_t ws_size,
                              hipStream_t stream) {
    const float* img = (const float*)d_in[0];  // [B,T,H,W] fp32
    const float* dx  = (const float*)d_in[1];  // [B,T]
    const float* dy  = (const float*)d_in[2];  // [B,T]
    // d_in[3] = winsize (unused)
    float* out = (float*)d_out;

    const int BT = in_sizes[1];                   // number of images (B*T)
    const int nblocks = BT * (HH / RB);           // one block per 16-row band

    translate_kernel<<<nblocks, 256, 0, stream>>>(img, dx, dy, out);
}